// Round 1
// baseline (520.721 us; speedup 1.0000x reference)
//
#include <hip/hip_runtime.h>
#include <math.h>

#define B 256
#define LC 400
#define LQ 50
#define D 128
#define CT 64

// ---------------------------------------------------------------------------
// K1: fused scores + dual softmax. One block (256 thr) per batch, ~148KB LDS.
// Phase A per tile: 4c x 7q GEMM (t<128, c rows cg+16i: bank-conflict-free)
//                   + sc bias (t in [128,192)) + register prefetch of next tile.
// Phase B: epilogue sS write + prefetch->LDS.
// Then col/row softmax stats in LDS, write S_bar + S_T once (no S_raw).
// ---------------------------------------------------------------------------
__global__ __launch_bounds__(256) void k_scores_softmax(
    const float* __restrict__ xc_g, const float* __restrict__ xq_g,
    const float* __restrict__ W0, const float* __restrict__ W1,
    const float* __restrict__ W2, const int* __restrict__ cont_len,
    const int* __restrict__ ques_len,
    float* __restrict__ S_bar, float* __restrict__ S_T)
{
    __shared__ float sS[LC * 51];                    // raw scores (scalar access)
    __shared__ __align__(16) float xq[56 * 132];     // scaled by W2 after bias
    __shared__ __align__(16) float xc[64 * 132];
    __shared__ float w[3 * D];
    __shared__ float scT[64];
    __shared__ float sq[56];
    __shared__ float rowmax[LC], rowinv[LC];
    __shared__ float colmax[LQ], colinv[LQ];
    __shared__ float red[256];

    const int b = blockIdx.x;
    const int t = threadIdx.x;
    const int clen = cont_len[b];
    const int qlen = ques_len[b];

    // ---- load xq + xc tile 0 + weights (all float4) ----
    const float4* xq4g = (const float4*)(xq_g + (size_t)b * LQ * D);
    for (int i = t; i < LQ * 32; i += 256)
        ((float4*)xq)[(i >> 5) * 33 + (i & 31)] = xq4g[i];
    {
        const float4* g0 = (const float4*)(xc_g + (size_t)b * LC * D);
        for (int i = t; i < 64 * 32; i += 256)
            ((float4*)xc)[(i >> 5) * 33 + (i & 31)] = g0[i];
    }
    if (t < D) { w[t] = W0[t]; w[D + t] = W1[t]; w[2 * D + t] = W2[t]; }
    __syncthreads();

    // ---- sq = raw xq . W1 ----
    if (t < LQ) {
        const float4* r = (const float4*)(xq + t * 132);
        const float4* wv = (const float4*)(w + D);
        float4 a = {0.f, 0.f, 0.f, 0.f};
#pragma unroll
        for (int d = 0; d < 32; ++d) {
            float4 u = r[d], v = wv[d];
            a.x += u.x * v.x; a.y += u.y * v.y; a.z += u.z * v.z; a.w += u.w * v.w;
        }
        sq[t] = a.x + a.y + a.z + a.w;
    }
    __syncthreads();
    // ---- scale xq by W2 in place (scores use xc.(W2*xq)) ----
    for (int i = t; i < LQ * D; i += 256)
        xq[(i >> 7) * 132 + (i & 127)] *= w[2 * D + (i & 127)];
    __syncthreads();

    const int qg = t & 7;
    const int cg = (t >> 3) & 15;

    for (int tile = 0; tile < 7; ++tile) {
        const int c0 = tile * 64;
        const int nc = min(64, LC - c0);

        // register prefetch of next tile (hides HBM under GEMM)
        float4 pf[8];
        const int c0n = c0 + 64;
        const int ncn = (tile < 6) ? min(64, LC - c0n) : 0;
        const float4* gn = (const float4*)(xc_g + ((size_t)b * LC + c0n) * D);
#pragma unroll
        for (int k = 0; k < 8; ++k) {
            const int i = t + k * 256;
            if (i < ncn * 32) pf[k] = gn[i];
        }

        float acc[4][7];
        if (t < 128) {
#pragma unroll
            for (int i = 0; i < 4; ++i)
#pragma unroll
                for (int j = 0; j < 7; ++j) acc[i][j] = 0.f;
            const float4* xc4 = (const float4*)xc;
            const float4* xq4 = (const float4*)xq;
#pragma unroll 4
            for (int d4 = 0; d4 < 32; ++d4) {
                const float4 a0 = xc4[(cg + 0)  * 33 + d4];
                const float4 a1 = xc4[(cg + 16) * 33 + d4];
                const float4 a2 = xc4[(cg + 32) * 33 + d4];
                const float4 a3 = xc4[(cg + 48) * 33 + d4];
#pragma unroll
                for (int j = 0; j < 7; ++j) {
                    const float4 bq = xq4[(qg * 7 + j) * 33 + d4];
                    acc[0][j] += a0.x*bq.x + a0.y*bq.y + a0.z*bq.z + a0.w*bq.w;
                    acc[1][j] += a1.x*bq.x + a1.y*bq.y + a1.z*bq.z + a1.w*bq.w;
                    acc[2][j] += a2.x*bq.x + a2.y*bq.y + a2.z*bq.z + a2.w*bq.w;
                    acc[3][j] += a3.x*bq.x + a3.y*bq.y + a3.z*bq.z + a3.w*bq.w;
                }
            }
        } else if (t < 192) {
            const int c = t - 128;
            if (c < nc) {
                const float4* r = (const float4*)(xc + c * 132);
                const float4* wv = (const float4*)w;
                float4 a = {0.f, 0.f, 0.f, 0.f};
#pragma unroll
                for (int d = 0; d < 32; ++d) {
                    float4 u = r[d], v = wv[d];
                    a.x += u.x*v.x; a.y += u.y*v.y; a.z += u.z*v.z; a.w += u.w*v.w;
                }
                scT[c] = a.x + a.y + a.z + a.w;
            }
        }
        __syncthreads();   // scT ready; all xc reads done

        if (t < 128) {
#pragma unroll
            for (int i = 0; i < 4; ++i) {
                const int c = cg + 16 * i;
                if (c < nc) {
                    const float sc_c = scT[c];
#pragma unroll
                    for (int j = 0; j < 7; ++j) {
                        const int q = qg * 7 + j;
                        if (q < LQ) sS[(c0 + c) * 51 + q] = acc[i][j] + sc_c + sq[q];
                    }
                }
            }
        }
        // write prefetched tile into xc (safe: GEMM reads complete)
#pragma unroll
        for (int k = 0; k < 8; ++k) {
            const int i = t + k * 256;
            if (i < ncn * 32) ((float4*)xc)[(i >> 5) * 33 + (i & 31)] = pf[k];
        }
        __syncthreads();
    }

    // ---- column stats (softmax over c < clen), 5 partials x 50 q ----
    const int qq_ = t % LQ;
    const int r_ = t / LQ;
    if (t < 250) {
        float m = -INFINITY;
        const int ce = min((r_ + 1) * 80, clen);
        for (int c = r_ * 80; c < ce; ++c) m = fmaxf(m, sS[c * 51 + qq_]);
        red[t] = m;
    }
    __syncthreads();
    if (t < LQ) {
        float m = red[t];
#pragma unroll
        for (int rr = 1; rr < 5; ++rr) m = fmaxf(m, red[rr * LQ + t]);
        colmax[t] = m;
    }
    __syncthreads();
    if (t < 250) {
        float s = 0.f;
        const float cm = colmax[qq_];
        const int ce = min((r_ + 1) * 80, clen);
        for (int c = r_ * 80; c < ce; ++c) s += __expf(sS[c * 51 + qq_] - cm);
        red[t] = s;
    }
    __syncthreads();
    if (t < LQ) {
        float s = red[t];
#pragma unroll
        for (int rr = 1; rr < 5; ++rr) s += red[rr * LQ + t];
        colinv[t] = 1.f / s;
    }
    // ---- row stats (softmax over q < qlen) ----
    for (int c = t; c < LC; c += 256) {
        float m = -INFINITY;
        for (int q = 0; q < qlen; ++q) m = fmaxf(m, sS[c * 51 + q]);
        float s = 0.f;
        for (int q = 0; q < qlen; ++q) s += __expf(sS[c * 51 + q] - m);
        rowmax[c] = m;
        rowinv[c] = 1.f / s;
    }
    __syncthreads();

    // ---- write S_bar (coalesced) ----
    float* Sb = S_bar + (size_t)b * LC * LQ;
    for (int i = t; i < LC * LQ; i += 256) {
        const int c = i / LQ, q = i - c * LQ;
        Sb[i] = (q < qlen) ? __expf(sS[c * 51 + q] - rowmax[c]) * rowinv[c] : 0.f;
    }
    // ---- write S_T (coalesced, transposed) ----
    float* STb = S_T + (size_t)b * LQ * LC;
    for (int i = t; i < LQ * LC; i += 256) {
        const int q = i / LC, c = i - q * LC;
        STb[i] = (c < clen) ? __expf(sS[c * 51 + q] - colmax[q]) * colinv[q] : 0.f;
    }
}

// ---------------------------------------------------------------------------
// K2: T[b] = S_T[b] @ x_cont[b]   (50x400 @ 400x128). One block per b.
// S_T staged into LDS via float4; xc streamed from global (L2/L3 hot).
// ---------------------------------------------------------------------------
__global__ __launch_bounds__(256) void k_qc(
    const float* __restrict__ S_T, const float* __restrict__ xc_g,
    float* __restrict__ T)
{
    __shared__ __align__(16) float sT[56 * 404];   // rows padded: 404 fl = 101x16B

    const int b = blockIdx.x;
    const int t = threadIdx.x;
    const float4* STb4 = (const float4*)(S_T + (size_t)b * LQ * LC);
    float4* sTw = (float4*)sT;
    for (int i = t; i < LQ * 100; i += 256)
        sTw[(i / 100) * 101 + (i % 100)] = STb4[i];
    __syncthreads();

    const int d4 = t & 31, qg = t >> 5;   // qg 0..7 owns q = qg*7+j
    float4 acc[7];
#pragma unroll
    for (int j = 0; j < 7; ++j) acc[j] = make_float4(0.f, 0.f, 0.f, 0.f);

    const float4* xcv = (const float4*)xc_g + (size_t)b * LC * 32 + d4;
    const float4* sT4 = (const float4*)sT;
    for (int c = 0; c < LC; c += 4) {
        const float4 x0 = xcv[(c + 0) * 32];
        const float4 x1 = xcv[(c + 1) * 32];
        const float4 x2 = xcv[(c + 2) * 32];
        const float4 x3 = xcv[(c + 3) * 32];
#pragma unroll
        for (int j = 0; j < 7; ++j) {
            const float4 wv = sT4[(qg * 7 + j) * 101 + (c >> 2)];
            acc[j].x += wv.x * x0.x + wv.y * x1.x + wv.z * x2.x + wv.w * x3.x;
            acc[j].y += wv.x * x0.y + wv.y * x1.y + wv.z * x2.y + wv.w * x3.y;
            acc[j].z += wv.x * x0.z + wv.y * x1.z + wv.z * x2.z + wv.w * x3.z;
            acc[j].w += wv.x * x0.w + wv.y * x1.w + wv.z * x2.w + wv.w * x3.w;
        }
    }
    float4* Tb = (float4*)T + (size_t)b * LQ * 32 + d4;
#pragma unroll
    for (int j = 0; j < 7; ++j) {
        const int qq = qg * 7 + j;
        if (qq < LQ) Tb[qq * 32] = acc[j];
    }
}

// ---------------------------------------------------------------------------
// K3: out[b,c,:] = [xc, c2q, xc*c2q, xc*q2c]. Grid (7 c-tiles, B), block 256.
// S_bar tile transposed into [q][c] LDS -> weights come as 2 broadcast b128
// reads per q-iter (was 8 scalar b32): main loop now VALU-bound.
// ---------------------------------------------------------------------------
#define FMA4(A, s, V) { A.x += (s) * V.x; A.y += (s) * V.y; A.z += (s) * V.z; A.w += (s) * V.w; }

__global__ __launch_bounds__(256) void k_out(
    const float* __restrict__ S_bar, const float* __restrict__ xq_g,
    const float* __restrict__ Tm, const float* __restrict__ xc_g,
    float* __restrict__ out)
{
    __shared__ __align__(16) float xqL[LQ * 132];
    __shared__ __align__(16) float TL[LQ * 132];
    __shared__ __align__(16) float sbT[LQ * 68];   // [q][c-tile], 68 fl = 17x16B

    const int b = blockIdx.y;
    const int c0 = blockIdx.x * CT;
    const int t = threadIdx.x;
    const int nc = min(CT, LC - c0);

    const float4* xq4g = (const float4*)(xq_g + (size_t)b * LQ * D);
    const float4* T4g  = (const float4*)(Tm + (size_t)b * LQ * D);
    for (int i = t; i < LQ * 32; i += 256) {
        const int row = i >> 5, col = i & 31;
        ((float4*)xqL)[row * 33 + col] = xq4g[i];
        ((float4*)TL)[row * 33 + col]  = T4g[i];
    }
    const float* sb_g = S_bar + (size_t)(b * LC + c0) * LQ;
    for (int i = t; i < nc * LQ; i += 256) {
        const int c = i / LQ, q = i - c * LQ;
        sbT[q * 68 + c] = sb_g[i];
    }
    __syncthreads();

    const int d4 = t & 31, cg = t >> 5;   // cg 0..7 owns 8 c rows
    float4 c2q[8], q2c[8];
#pragma unroll
    for (int i = 0; i < 8; ++i) {
        c2q[i] = make_float4(0.f, 0.f, 0.f, 0.f);
        q2c[i] = make_float4(0.f, 0.f, 0.f, 0.f);
    }
    const float4* xq4 = (const float4*)xqL;
    const float4* T4  = (const float4*)TL;
    const float4* sb4 = (const float4*)sbT;
    const int cb2 = cg * 2;
    for (int qq = 0; qq < LQ; ++qq) {
        const float4 xv = xq4[qq * 33 + d4];
        const float4 tv = T4[qq * 33 + d4];
        const float4 s0 = sb4[qq * 17 + cb2];
        const float4 s1 = sb4[qq * 17 + cb2 + 1];
        FMA4(c2q[0], s0.x, xv); FMA4(q2c[0], s0.x, tv);
        FMA4(c2q[1], s0.y, xv); FMA4(q2c[1], s0.y, tv);
        FMA4(c2q[2], s0.z, xv); FMA4(q2c[2], s0.z, tv);
        FMA4(c2q[3], s0.w, xv); FMA4(q2c[3], s0.w, tv);
        FMA4(c2q[4], s1.x, xv); FMA4(q2c[4], s1.x, tv);
        FMA4(c2q[5], s1.y, xv); FMA4(q2c[5], s1.y, tv);
        FMA4(c2q[6], s1.z, xv); FMA4(q2c[6], s1.z, tv);
        FMA4(c2q[7], s1.w, xv); FMA4(q2c[7], s1.w, tv);
    }

    const int cbase = cg * 8;
    const float4* xcv = (const float4*)xc_g;
    float4* out4 = (float4*)out;
#pragma unroll
    for (int i = 0; i < 8; ++i) {
        const int c = cbase + i;
        if (c < nc) {
            const int row = b * LC + c0 + c;
            const float4 xc = xcv[(size_t)row * 32 + d4];
            float4* o = out4 + (size_t)row * 128 + d4;
            o[0] = xc;
            o[32] = c2q[i];
            o[64] = make_float4(xc.x * c2q[i].x, xc.y * c2q[i].y,
                                xc.z * c2q[i].z, xc.w * c2q[i].w);
            o[96] = make_float4(xc.x * q2c[i].x, xc.y * q2c[i].y,
                                xc.z * q2c[i].z, xc.w * q2c[i].w);
        }
    }
}

// ---------------------------------------------------------------------------
extern "C" void kernel_launch(void* const* d_in, const int* in_sizes, int n_in,
                              void* d_out, int out_size, void* d_ws, size_t ws_size,
                              hipStream_t stream)
{
    (void)in_sizes; (void)n_in; (void)out_size; (void)ws_size;
    const float* x_cont = (const float*)d_in[0];
    const float* x_ques = (const float*)d_in[1];
    const float* W0 = (const float*)d_in[2];
    const float* W1 = (const float*)d_in[3];
    const float* W2 = (const float*)d_in[4];
    const int* cont_len = (const int*)d_in[5];
    const int* ques_len = (const int*)d_in[6];

    float* out = (float*)d_out;
    float* out_res  = out;                                  // B*LC*4D
    float* out_Sbar = out + (size_t)B * LC * 4 * D;         // B*LC*LQ
    float* out_ST   = out_Sbar + (size_t)B * LC * LQ;       // B*LQ*LC
    float* Tws = (float*)d_ws;                              // B*LQ*D floats

    k_scores_softmax<<<B, 256, 0, stream>>>(x_cont, x_ques, W0, W1, W2,
                                            cont_len, ques_len, out_Sbar, out_ST);
    k_qc<<<B, 256, 0, stream>>>(out_ST, x_cont, Tws);
    k_out<<<dim3(7, B), 256, 0, stream>>>(out_Sbar, x_ques, Tws, x_cont, out_res);
}

// Round 2
// 446.665 us; speedup vs baseline: 1.1658x; 1.1658x over previous
//
#include <hip/hip_runtime.h>
#include <math.h>

#define B 256
#define LC 400
#define LQ 50
#define D 128
#define CT 64

// ---------------------------------------------------------------------------
// K1: scores tile GEMM + ROW softmax fused. Grid (7, B), 256 thr, ~79KB LDS
// (2 blocks/CU). Writes S_bar directly (coalesced) and raw scores transposed
// into the S_T buffer (col-softmaxed later by K2). Raw S never hits HBM in
// [c][q] layout.
// ---------------------------------------------------------------------------
__global__ __launch_bounds__(256) void k_scores_rowsm(
    const float* __restrict__ xc_g, const float* __restrict__ xq_g,
    const float* __restrict__ W0, const float* __restrict__ W1,
    const float* __restrict__ W2, const int* __restrict__ ques_len,
    float* __restrict__ S_bar, float* __restrict__ S_Traw)
{
    __shared__ __align__(16) float xq[56 * 132];   // scaled by W2 after sq
    __shared__ __align__(16) float xc[CT * 132];
    __shared__ float w[3 * D];
    __shared__ float sq[56], sc[CT];
    __shared__ float sS[CT * 51];
    __shared__ float rowm[CT], rowi[CT];

    const int b = blockIdx.y;
    const int c0 = blockIdx.x * CT;
    const int t = threadIdx.x;
    const int nc = min(CT, LC - c0);
    const int qlen = ques_len[b];

    // ---- stage xq, xc tile, weights (all float4) ----
    const float4* xq4g = (const float4*)(xq_g + (size_t)b * LQ * D);
    for (int i = t; i < LQ * 32; i += 256)
        ((float4*)xq)[(i >> 5) * 33 + (i & 31)] = xq4g[i];
    const float4* xc4g = (const float4*)(xc_g + (size_t)(b * LC + c0) * D);
    for (int i = t; i < nc * 32; i += 256)
        ((float4*)xc)[(i >> 5) * 33 + (i & 31)] = xc4g[i];
    if (t < D) { w[t] = W0[t]; w[D + t] = W1[t]; w[2 * D + t] = W2[t]; }
    __syncthreads();

    // ---- bias terms from raw xq / xc ----
    if (t < LQ) {
        const float4* r = (const float4*)(xq + t * 132);
        const float4* wv = (const float4*)(w + D);
        float4 a = {0.f, 0.f, 0.f, 0.f};
#pragma unroll
        for (int d = 0; d < 32; ++d) {
            float4 u = r[d], v = wv[d];
            a.x += u.x * v.x; a.y += u.y * v.y; a.z += u.z * v.z; a.w += u.w * v.w;
        }
        sq[t] = a.x + a.y + a.z + a.w;
    } else if (t >= 64 && t < 64 + CT) {
        const int c = t - 64;
        if (c < nc) {
            const float4* r = (const float4*)(xc + c * 132);
            const float4* wv = (const float4*)w;
            float4 a = {0.f, 0.f, 0.f, 0.f};
#pragma unroll
            for (int d = 0; d < 32; ++d) {
                float4 u = r[d], v = wv[d];
                a.x += u.x * v.x; a.y += u.y * v.y; a.z += u.z * v.z; a.w += u.w * v.w;
            }
            sc[c] = a.x + a.y + a.z + a.w;
        }
    }
    __syncthreads();
    // ---- scale xq rows by W2 in place (s_f = xc . (W2*xq)) ----
    for (int i = t; i < LQ * D; i += 256)
        xq[(i >> 7) * 132 + (i & 127)] *= w[2 * D + (i & 127)];
    __syncthreads();

    // ---- GEMM: thread (cg,qg) owns c = 2cg,2cg+1 ; q = qg*7+j ----
    const int qg = t & 7, cg = t >> 3;
    const int cA = cg * 2;
    if (cA < nc) {
        float accA[7] = {0, 0, 0, 0, 0, 0, 0};
        float accB[7] = {0, 0, 0, 0, 0, 0, 0};
        const float4* xc4 = (const float4*)xc;
        const float4* xq4 = (const float4*)xq;
#pragma unroll 8
        for (int d4 = 0; d4 < 32; ++d4) {
            const float4 a0 = xc4[cA * 33 + d4];
            const float4 a1 = xc4[(cA + 1) * 33 + d4];
#pragma unroll
            for (int j = 0; j < 7; ++j) {
                const float4 bq = xq4[(qg * 7 + j) * 33 + d4];
                accA[j] += a0.x * bq.x + a0.y * bq.y + a0.z * bq.z + a0.w * bq.w;
                accB[j] += a1.x * bq.x + a1.y * bq.y + a1.z * bq.z + a1.w * bq.w;
            }
        }
        const float scA = sc[cA], scB = sc[cA + 1];
#pragma unroll
        for (int j = 0; j < 7; ++j) {
            const int q = qg * 7 + j;
            if (q < LQ) {
                sS[cA * 51 + q] = accA[j] + scA + sq[q];
                sS[(cA + 1) * 51 + q] = accB[j] + scB + sq[q];
            }
        }
    }
    __syncthreads();

    // ---- row softmax stats (over q < qlen), one thread per c-row ----
    if (t < nc) {
        float m = -INFINITY;
        for (int q = 0; q < qlen; ++q) m = fmaxf(m, sS[t * 51 + q]);
        float s = 0.f;
        for (int q = 0; q < qlen; ++q) s += __expf(sS[t * 51 + q] - m);
        rowm[t] = m;
        rowi[t] = 1.f / s;
    }
    __syncthreads();

    // ---- S_bar write (final, coalesced) ----
    float* Sb = S_bar + (size_t)(b * LC + c0) * LQ;
    for (int i = t; i < nc * LQ; i += 256) {
        const int c = i / LQ, q = i - c * LQ;
        Sb[i] = (q < qlen) ? __expf(sS[c * 51 + q] - rowm[c]) * rowi[c] : 0.f;
    }
    // ---- raw S^T write (coalesced 256B runs) ----
    float* STb = S_Traw + (size_t)b * LQ * LC + c0;
    for (int i = t; i < LQ * 64; i += 256) {
        const int q = i >> 6, c = i & 63;
        if (c < nc) STb[q * LC + c] = sS[c * 51 + q];
    }
}

// ---------------------------------------------------------------------------
// K2: COLUMN softmax (over c, mask cont_len) on raw S^T staged in LDS, write
// final S_T out, then T[b] = S_T[b] @ x_cont[b]. One block (512 thr) per b:
// 91KB LDS -> 1 block/CU, 8 waves (2/SIMD).
// ---------------------------------------------------------------------------
__global__ __launch_bounds__(512) void k_colsm_qc(
    float* __restrict__ S_T, const float* __restrict__ xc_g,
    const int* __restrict__ cont_len, float* __restrict__ T)
{
    __shared__ __align__(16) float sT[56 * 404];   // rows padded: 404 fl = 101x16B
    __shared__ float red[256];
    __shared__ float colmax[LQ], colinv[LQ];

    const int b = blockIdx.x;
    const int t = threadIdx.x;
    const int clen = cont_len[b];
    float* STb = S_T + (size_t)b * LQ * LC;

    // stage raw S^T (float4)
    const float4* STb4 = (const float4*)STb;
    float4* sTw = (float4*)sT;
    for (int i = t; i < LQ * 100; i += 512)
        sTw[(i / 100) * 101 + (i % 100)] = STb4[i];
    __syncthreads();

    // col stats: 5 partials per q-row
    const int qr = t / 5, g = t - qr * 5;
    if (t < 250) {
        float m = -INFINITY;
        const int ce = min((g + 1) * 80, clen);
        for (int c = g * 80; c < ce; ++c) m = fmaxf(m, sT[qr * 404 + c]);
        red[t] = m;
    }
    __syncthreads();
    if (t < LQ) {
        float m = red[t * 5];
#pragma unroll
        for (int k = 1; k < 5; ++k) m = fmaxf(m, red[t * 5 + k]);
        colmax[t] = m;
    }
    __syncthreads();
    if (t < 250) {
        float s = 0.f;
        const float cm = colmax[qr];
        const int ce = min((g + 1) * 80, clen);
        for (int c = g * 80; c < ce; ++c) s += __expf(sT[qr * 404 + c] - cm);
        red[t] = s;
    }
    __syncthreads();
    if (t < LQ) {
        float s = red[t * 5];
#pragma unroll
        for (int k = 1; k < 5; ++k) s += red[t * 5 + k];
        colinv[t] = 1.f / s;
    }
    __syncthreads();

    // normalize in LDS + write final S_T (coalesced, in place)
    for (int i = t; i < LQ * LC; i += 512) {
        const int q = i / LC, c = i - q * LC;
        const float v = (c < clen) ? __expf(sT[q * 404 + c] - colmax[q]) * colinv[q] : 0.f;
        sT[q * 404 + c] = v;
        STb[i] = v;
    }
    __syncthreads();

    // GEMM: T = S_T @ xc. 512 thr: d4 = t&31, qg = t>>5 owns q = qg*4+j
    const int d4 = t & 31, qg = t >> 5;
    const int qb = qg * 4;
    float4 acc[4];
#pragma unroll
    for (int j = 0; j < 4; ++j) acc[j] = make_float4(0.f, 0.f, 0.f, 0.f);

    const float4* xcv = (const float4*)xc_g + (size_t)b * LC * 32 + d4;
    const float4* sT4 = (const float4*)sT;
    for (int c = 0; c < LC; c += 4) {
        const float4 x0 = xcv[(c + 0) * 32];
        const float4 x1 = xcv[(c + 1) * 32];
        const float4 x2 = xcv[(c + 2) * 32];
        const float4 x3 = xcv[(c + 3) * 32];
#pragma unroll
        for (int j = 0; j < 4; ++j) {
            const int q = min(qb + j, LQ - 1);
            const float4 wv = sT4[q * 101 + (c >> 2)];
            acc[j].x += wv.x * x0.x + wv.y * x1.x + wv.z * x2.x + wv.w * x3.x;
            acc[j].y += wv.x * x0.y + wv.y * x1.y + wv.z * x2.y + wv.w * x3.y;
            acc[j].z += wv.x * x0.z + wv.y * x1.z + wv.z * x2.z + wv.w * x3.z;
            acc[j].w += wv.x * x0.w + wv.y * x1.w + wv.z * x2.w + wv.w * x3.w;
        }
    }
    float4* Tb = (float4*)T + (size_t)b * LQ * 32 + d4;
#pragma unroll
    for (int j = 0; j < 4; ++j) {
        const int q = qb + j;
        if (q < LQ) Tb[q * 32] = acc[j];
    }
}

// ---------------------------------------------------------------------------
// K3: out[b,c,:] = [xc, c2q, xc*c2q, xc*q2c]. Grid (7 c-tiles, B), block 256.
// S_bar tile transposed into [q][c] LDS -> weights come as 2 broadcast b128
// reads per q-iter: main loop VALU-bound; epilogue HBM-store-bound.
// ---------------------------------------------------------------------------
#define FMA4(A, s, V) { A.x += (s) * V.x; A.y += (s) * V.y; A.z += (s) * V.z; A.w += (s) * V.w; }

__global__ __launch_bounds__(256) void k_out(
    const float* __restrict__ S_bar, const float* __restrict__ xq_g,
    const float* __restrict__ Tm, const float* __restrict__ xc_g,
    float* __restrict__ out)
{
    __shared__ __align__(16) float xqL[LQ * 132];
    __shared__ __align__(16) float TL[LQ * 132];
    __shared__ __align__(16) float sbT[LQ * 68];   // [q][c-tile], 68 fl = 17x16B

    const int b = blockIdx.y;
    const int c0 = blockIdx.x * CT;
    const int t = threadIdx.x;
    const int nc = min(CT, LC - c0);

    const float4* xq4g = (const float4*)(xq_g + (size_t)b * LQ * D);
    const float4* T4g  = (const float4*)(Tm + (size_t)b * LQ * D);
    for (int i = t; i < LQ * 32; i += 256) {
        const int row = i >> 5, col = i & 31;
        ((float4*)xqL)[row * 33 + col] = xq4g[i];
        ((float4*)TL)[row * 33 + col]  = T4g[i];
    }
    const float* sb_g = S_bar + (size_t)(b * LC + c0) * LQ;
    for (int i = t; i < nc * LQ; i += 256) {
        const int c = i / LQ, q = i - c * LQ;
        sbT[q * 68 + c] = sb_g[i];
    }
    __syncthreads();

    const int d4 = t & 31, cg = t >> 5;   // cg 0..7 owns 8 c rows
    float4 c2q[8], q2c[8];
#pragma unroll
    for (int i = 0; i < 8; ++i) {
        c2q[i] = make_float4(0.f, 0.f, 0.f, 0.f);
        q2c[i] = make_float4(0.f, 0.f, 0.f, 0.f);
    }
    const float4* xq4 = (const float4*)xqL;
    const float4* T4  = (const float4*)TL;
    const float4* sb4 = (const float4*)sbT;
    const int cb2 = cg * 2;
    for (int qq = 0; qq < LQ; ++qq) {
        const float4 xv = xq4[qq * 33 + d4];
        const float4 tv = T4[qq * 33 + d4];
        const float4 s0 = sb4[qq * 17 + cb2];
        const float4 s1 = sb4[qq * 17 + cb2 + 1];
        FMA4(c2q[0], s0.x, xv); FMA4(q2c[0], s0.x, tv);
        FMA4(c2q[1], s0.y, xv); FMA4(q2c[1], s0.y, tv);
        FMA4(c2q[2], s0.z, xv); FMA4(q2c[2], s0.z, tv);
        FMA4(c2q[3], s0.w, xv); FMA4(q2c[3], s0.w, tv);
        FMA4(c2q[4], s1.x, xv); FMA4(q2c[4], s1.x, tv);
        FMA4(c2q[5], s1.y, xv); FMA4(q2c[5], s1.y, tv);
        FMA4(c2q[6], s1.z, xv); FMA4(q2c[6], s1.z, tv);
        FMA4(c2q[7], s1.w, xv); FMA4(q2c[7], s1.w, tv);
    }

    const int cbase = cg * 8;
    const float4* xcv = (const float4*)xc_g;
    float4* out4 = (float4*)out;
#pragma unroll
    for (int i = 0; i < 8; ++i) {
        const int c = cbase + i;
        if (c < nc) {
            const int row = b * LC + c0 + c;
            const float4 xc = xcv[(size_t)row * 32 + d4];
            float4* o = out4 + (size_t)row * 128 + d4;
            o[0] = xc;
            o[32] = c2q[i];
            o[64] = make_float4(xc.x * c2q[i].x, xc.y * c2q[i].y,
                                xc.z * c2q[i].z, xc.w * c2q[i].w);
            o[96] = make_float4(xc.x * q2c[i].x, xc.y * q2c[i].y,
                                xc.z * q2c[i].z, xc.w * q2c[i].w);
        }
    }
}

// ---------------------------------------------------------------------------
extern "C" void kernel_launch(void* const* d_in, const int* in_sizes, int n_in,
                              void* d_out, int out_size, void* d_ws, size_t ws_size,
                              hipStream_t stream)
{
    (void)in_sizes; (void)n_in; (void)out_size; (void)ws_size;
    const float* x_cont = (const float*)d_in[0];
    const float* x_ques = (const float*)d_in[1];
    const float* W0 = (const float*)d_in[2];
    const float* W1 = (const float*)d_in[3];
    const float* W2 = (const float*)d_in[4];
    const int* cont_len = (const int*)d_in[5];
    const int* ques_len = (const int*)d_in[6];

    float* out = (float*)d_out;
    float* out_res  = out;                                  // B*LC*4D
    float* out_Sbar = out + (size_t)B * LC * 4 * D;         // B*LC*LQ
    float* out_ST   = out_Sbar + (size_t)B * LC * LQ;       // B*LQ*LC
    float* Tws = (float*)d_ws;                              // B*LQ*D floats

    k_scores_rowsm<<<dim3(7, B), 256, 0, stream>>>(x_cont, x_ques, W0, W1, W2,
                                                   ques_len, out_Sbar, out_ST);
    k_colsm_qc<<<B, 512, 0, stream>>>(out_ST, x_cont, cont_len, Tws);
    k_out<<<dim3(7, B), 256, 0, stream>>>(out_Sbar, x_ques, Tws, x_cont, out_res);
}